// Round 10
// baseline (17401.575 us; speedup 1.0000x reference)
//
#include <hip/hip_runtime.h>
#include <math.h>

// Problem constants
#define NN 50000
#define NE 200000

// ---------------------------------------------------------------------------
// Init: flag=1 (assume int64 until disproven), cnt=0
// ---------------------------------------------------------------------------
__global__ __launch_bounds__(256) void initflag_kernel(int* __restrict__ flag,
                                                       int* __restrict__ cnt, int n) {
    int i = blockIdx.x * 256 + threadIdx.x;
    if (i == 0) flag[0] = 1;
    if (i < n) cnt[i] = 0;
}

// If ANY odd int32 slot among the first 4096 pairs is nonzero, data is int32.
// (int64 values are all < 2^31 here, so their high words are exactly 0.)
__global__ __launch_bounds__(256) void sniff_kernel(const int* __restrict__ ei,
                                                    int* __restrict__ flag) {
    int t = threadIdx.x;
    int nz = 0;
    for (int i = t; i < 4096; i += 256) nz |= (ei[2 * i + 1] != 0);
    if (nz) flag[0] = 0;
}

// Normalize edge_index to int32 in edg[0..2E), clamped to [0, NN)
__global__ __launch_bounds__(256) void cvt_edges_kernel(const int* __restrict__ ei,
                                                        const int* __restrict__ flag,
                                                        int* __restrict__ edg, int n2e) {
    int i = blockIdx.x * 256 + threadIdx.x;
    if (i < n2e) {
        int v = flag[0] ? ei[2 * i] : ei[i];
        if ((unsigned)v >= (unsigned)NN) v = 0;
        edg[i] = v;
    }
}

// ---------------------------------------------------------------------------
// CSR build: histogram of dst, exclusive scan, counting-sort fill
// ---------------------------------------------------------------------------
__global__ __launch_bounds__(256) void hist_kernel(const int* __restrict__ dst,
                                                   int* __restrict__ cnt, int E) {
    int e = blockIdx.x * 256 + threadIdx.x;
    if (e < E) atomicAdd(&cnt[dst[e]], 1);
}

__global__ __launch_bounds__(1024) void scan_kernel(const int* __restrict__ cnt,
                                                    int* __restrict__ off, int n) {
    __shared__ int lds[1024];
    __shared__ int carry;
    int t = threadIdx.x;
    if (t == 0) { carry = 0; off[0] = 0; }
    __syncthreads();
    for (int base = 0; base < n; base += 1024) {
        int v = (base + t < n) ? cnt[base + t] : 0;
        lds[t] = v;
        __syncthreads();
        for (int s = 1; s < 1024; s <<= 1) {
            int x = (t >= s) ? lds[t - s] : 0;
            __syncthreads();
            lds[t] += x;
            __syncthreads();
        }
        int inc = lds[t] + carry;           // inclusive scan + running carry
        if (base + t < n) off[base + t + 1] = inc;
        __syncthreads();                    // everyone has read `carry`
        if (t == 1023) carry = inc;
        __syncthreads();
    }
}

__global__ __launch_bounds__(256) void initcur_kernel(const int* __restrict__ off,
                                                      int* __restrict__ cur, int n) {
    int i = blockIdx.x * 256 + threadIdx.x;
    if (i < n) cur[i] = off[i];
}

__global__ __launch_bounds__(256) void fillcsr_kernel(const int* __restrict__ dst,
                                                      int* __restrict__ cur,
                                                      int* __restrict__ csre, int E) {
    int e = blockIdx.x * 256 + threadIdx.x;
    if (e < E) {
        int p = atomicAdd(&cur[dst[e]], 1);
        csre[p] = e;
    }
}

// ---------------------------------------------------------------------------
// Input prep: xc0 = [x(5)|sdf(1)|na(1)]; fixed columns of ping-pong buffers.
// Buffer row layout [516]: [fy(3) | out(512) | na(1)]
//   - 513-wide layers use cols 3..515 ([out|na])
//   - 516-wide layer (c0) uses the whole row
// ---------------------------------------------------------------------------
__global__ __launch_bounds__(256) void build_xc0_kernel(const float* __restrict__ x,
                                                        const float* __restrict__ sdf,
                                                        const float* __restrict__ na,
                                                        float* __restrict__ xc0, int n) {
    int i = blockIdx.x * 256 + threadIdx.x;
    if (i >= n) return;
    float* r = xc0 + (size_t)i * 7;
    const float* xr = x + (size_t)i * 5;
    r[0] = xr[0]; r[1] = xr[1]; r[2] = xr[2]; r[3] = xr[3]; r[4] = xr[4];
    r[5] = sdf[i];
    r[6] = na[i];
}

__global__ __launch_bounds__(256) void prep_bufs_kernel(const float* __restrict__ na,
                                                        const float* __restrict__ fy,
                                                        float* __restrict__ bufA,
                                                        float* __restrict__ bufB, int n) {
    int i = blockIdx.x * 256 + threadIdx.x;
    if (i >= n) return;
    float v = na[i];
    bufA[(size_t)i * 516 + 515] = v;
    bufB[(size_t)i * 516 + 515] = v;
    bufA[(size_t)i * 516 + 0] = fy[(size_t)i * 3 + 0];   // fy only consumed from A (c0 input)
    bufA[(size_t)i * 516 + 1] = fy[(size_t)i * 3 + 1];
    bufA[(size_t)i * 516 + 2] = fy[(size_t)i * 3 + 2];
}

// ---------------------------------------------------------------------------
// aggr[r, c] = sum_{e: dst=node0+r} relu(ea[e]·win[c] + bin[c]) * xc[src[e]*ldx + c/3]
// Block: 256 threads, 8 nodes. Thread owns columns {t + 256*kc}; win rows in regs.
// ---------------------------------------------------------------------------
template <int KC>
__global__ __launch_bounds__(256) void aggr_kernel(const float* __restrict__ xc, int ldx, int C,
                                                   const float* __restrict__ ea,
                                                   const int* __restrict__ src,
                                                   const int* __restrict__ off,
                                                   const int* __restrict__ csre,
                                                   const float* __restrict__ win,
                                                   const float* __restrict__ bin,
                                                   float* __restrict__ aggr,
                                                   int node0, int rows) {
    int t = threadIdx.x;
    int SC = 3 * C;
    float wr[KC][6];
    float br[KC];
    int ci[KC];
    bool ok[KC];
#pragma unroll
    for (int kc = 0; kc < KC; ++kc) {
        int c = t + 256 * kc;
        ok[kc] = (c < SC);
        ci[kc] = c / 3;
        if (ok[kc]) {
            const float* w = win + (size_t)c * 6;
#pragma unroll
            for (int q = 0; q < 6; ++q) wr[kc][q] = w[q];
            br[kc] = bin[c];
        } else {
            ci[kc] = 0;
#pragma unroll
            for (int q = 0; q < 6; ++q) wr[kc][q] = 0.f;
            br[kc] = 0.f;
        }
    }
    int nb0 = blockIdx.x * 8;
    for (int nb = 0; nb < 8; ++nb) {
        int r = nb0 + nb;
        if (r >= rows) break;
        int node = node0 + r;
        float acc[KC];
#pragma unroll
        for (int kc = 0; kc < KC; ++kc) acc[kc] = 0.f;
        int e0 = off[node], e1 = off[node + 1];
        for (int ie = e0; ie < e1; ++ie) {
            int e = csre[ie];
            const float* er = ea + (size_t)e * 6;
            float a0 = er[0], a1 = er[1], a2 = er[2], a3 = er[3], a4 = er[4], a5 = er[5];
            int s = src[e];
            const float* xr = xc + (size_t)s * ldx;
#pragma unroll
            for (int kc = 0; kc < KC; ++kc) {
                if (ok[kc]) {
                    float sc = br[kc];
                    sc = fmaf(a0, wr[kc][0], sc);
                    sc = fmaf(a1, wr[kc][1], sc);
                    sc = fmaf(a2, wr[kc][2], sc);
                    sc = fmaf(a3, wr[kc][3], sc);
                    sc = fmaf(a4, wr[kc][4], sc);
                    sc = fmaf(a5, wr[kc][5], sc);
                    sc = fmaxf(sc, 0.f);
                    acc[kc] = fmaf(sc, xr[ci[kc]], acc[kc]);
                }
            }
        }
        float* ar = aggr + (size_t)r * SC;
#pragma unroll
        for (int kc = 0; kc < KC; ++kc) {
            int c = t + 256 * kc;
            if (c < SC) ar[c] = acc[kc];
        }
    }
}

// ---------------------------------------------------------------------------
// out[m, ocol0+n] = relu?(tanh(A[m,:]·W[n,:] + bias[n])) for n in [n0, n0+128)
// fp32 tiled GEMM: BM=BN=128, BK=16, 256 threads, 8x8 micro-tile.
// LDS tiles transposed [BK][BM+4] (pad 132: float4-aligned, write conflicts free)
// ---------------------------------------------------------------------------
template <bool RELU>
__global__ __launch_bounds__(256) void gemm_tanh_kernel(const float* __restrict__ A,
                                                        const float* __restrict__ W,
                                                        const float* __restrict__ bias,
                                                        float* __restrict__ out,
                                                        int M, int K, int ostride, int ocol0) {
    __shared__ float As[16][132];
    __shared__ float Bs[16][132];
    int t = threadIdx.x;
    int m0 = blockIdx.x * 128;
    int n0 = blockIdx.y * 128;
    int tx = t & 15, ty = t >> 4;
    int kk0 = t & 15;   // k-column this thread loads
    int r0 = t >> 4;    // base row this thread loads
    float acc[8][8];
#pragma unroll
    for (int i = 0; i < 8; ++i)
#pragma unroll
        for (int j = 0; j < 8; ++j) acc[i][j] = 0.f;

    for (int k0 = 0; k0 < K; k0 += 16) {
        int gk = k0 + kk0;
        bool kok = (gk < K);
#pragma unroll
        for (int j = 0; j < 8; ++j) {
            int r = r0 + 16 * j;
            int gm = m0 + r;
            As[kk0][r] = (kok && gm < M) ? A[(size_t)gm * K + gk] : 0.f;
            int gn = n0 + r;  // always < 512 given grid.y = 4
            Bs[kk0][r] = kok ? W[(size_t)gn * K + gk] : 0.f;
        }
        __syncthreads();
#pragma unroll
        for (int kk = 0; kk < 16; ++kk) {
            float a[8], b[8];
            *(float4*)&a[0] = *(const float4*)&As[kk][ty * 8];
            *(float4*)&a[4] = *(const float4*)&As[kk][ty * 8 + 4];
            *(float4*)&b[0] = *(const float4*)&Bs[kk][tx * 8];
            *(float4*)&b[4] = *(const float4*)&Bs[kk][tx * 8 + 4];
#pragma unroll
            for (int i = 0; i < 8; ++i)
#pragma unroll
                for (int j = 0; j < 8; ++j) acc[i][j] = fmaf(a[i], b[j], acc[i][j]);
        }
        __syncthreads();
    }

#pragma unroll
    for (int i = 0; i < 8; ++i) {
        int gm = m0 + ty * 8 + i;
        if (gm < M) {
#pragma unroll
            for (int j = 0; j < 8; ++j) {
                int gn = n0 + tx * 8 + j;
                float v = tanhf(acc[i][j] + bias[gn]);
                if (RELU) v = fmaxf(v, 0.f);
                out[(size_t)gm * ostride + ocol0 + gn] = v;
            }
        }
    }
}

// ---------------------------------------------------------------------------
// Final layer: out[b, 0..2] = tanh(A[b,:]·W[o,:] + bias[o]) — one block per row
// ---------------------------------------------------------------------------
__global__ __launch_bounds__(256) void gemm_out3_kernel(const float* __restrict__ A,
                                                        const float* __restrict__ W,
                                                        const float* __restrict__ bias,
                                                        float* __restrict__ out, int K) {
    int n = blockIdx.x;
    int t = threadIdx.x;
    const float* ar = A + (size_t)n * K;
    float s0 = 0.f, s1 = 0.f, s2 = 0.f;
    for (int k = t; k < K; k += 256) {
        float a = ar[k];
        s0 = fmaf(a, W[k], s0);
        s1 = fmaf(a, W[K + k], s1);
        s2 = fmaf(a, W[2 * K + k], s2);
    }
#pragma unroll
    for (int d = 32; d >= 1; d >>= 1) {
        s0 += __shfl_down(s0, d, 64);
        s1 += __shfl_down(s1, d, 64);
        s2 += __shfl_down(s2, d, 64);
    }
    __shared__ float red[4][3];
    int lane = t & 63, w = t >> 6;
    if (lane == 0) { red[w][0] = s0; red[w][1] = s1; red[w][2] = s2; }
    __syncthreads();
    if (t == 0) {
        float r0 = red[0][0] + red[1][0] + red[2][0] + red[3][0];
        float r1 = red[0][1] + red[1][1] + red[2][1] + red[3][1];
        float r2 = red[0][2] + red[1][2] + red[2][2] + red[3][2];
        out[(size_t)n * 3 + 0] = tanhf(r0 + bias[0]);
        out[(size_t)n * 3 + 1] = tanhf(r1 + bias[1]);
        out[(size_t)n * 3 + 2] = tanhf(r2 + bias[2]);
    }
}

__global__ __launch_bounds__(256) void zero_out_kernel(float* __restrict__ o, int n) {
    int i = blockIdx.x * 256 + threadIdx.x;
    if (i < n) o[i] = 0.f;
}

// ---------------------------------------------------------------------------
extern "C" void kernel_launch(void* const* d_in, const int* in_sizes, int n_in,
                              void* d_out, int out_size, void* d_ws, size_t ws_size,
                              hipStream_t stream) {
    const int N = NN, E = NE;
    const float* x   = (const float*)d_in[0];
    const float* sdf = (const float*)d_in[1];
    const float* na  = (const float*)d_in[2];
    const float* ea  = (const float*)d_in[3];
    const float* fy  = (const float*)d_in[4];
    const int*   ei  = (const int*)d_in[5];   // [2][E]: src then dst (dtype sniffed)
    const float* win_[6];
    const float* bin_[6];
    const float* wout_[6];
    const float* bout_[6];
    for (int l = 0; l < 6; ++l) {
        win_[l]  = (const float*)d_in[6 + 4 * l + 0];
        bin_[l]  = (const float*)d_in[6 + 4 * l + 1];
        wout_[l] = (const float*)d_in[6 + 4 * l + 2];
        bout_[l] = (const float*)d_in[6 + 4 * l + 3];
    }

    // ---- ws-adaptive layout ----
    // fixed: bufA[N,516] + bufB[N,516] + xc0[N,7] + ints; aggr gets the remainder,
    // and layers run in node-chunks sized so aggr fits.
    char* base = (char*)d_ws;
    float* bufA = (float*)base;
    float* bufB = bufA + (size_t)N * 516;
    float* xc0  = bufB + (size_t)N * 516;
    int* off  = (int*)(xc0 + (size_t)N * 7);
    int* cnt  = off + (N + 1);
    int* cur  = cnt + N;
    int* csre = cur + N;
    int* edg  = csre + E;          // normalized int32 edges [2E]
    int* flag = edg + 2 * E;
    char* aggr_base = (char*)(flag + 1);
    aggr_base += (64 - ((size_t)(aggr_base - base) & 63)) & 63;   // 64B align
    float* aggr = (float*)aggr_base;
    size_t used = (size_t)(aggr_base - base);

    int chunk = 0;
    if (ws_size > used) {
        size_t af = (ws_size - used) / 4;      // floats available for aggr
        size_t c = af / 1548;                  // rows at widest SC
        if (c >= (size_t)N) chunk = N;
        else if (c >= 128) chunk = (int)(c / 128) * 128;
        else if (c >= 1) chunk = (int)c;
    }
    if (chunk <= 0) {   // ws too small — fail loudly with wrong-but-safe output
        zero_out_kernel<<<(out_size + 255) / 256, 256, 0, stream>>>((float*)d_out, out_size);
        return;
    }

    const int* src = edg;
    const int* dst = edg + E;
    int gE = (E + 255) / 256;
    int gN = (N + 255) / 256;
    int g2E = (2 * E + 255) / 256;

    // Edge normalize + CSR build
    initflag_kernel<<<gN, 256, 0, stream>>>(flag, cnt, N);
    sniff_kernel<<<1, 256, 0, stream>>>(ei, flag);
    cvt_edges_kernel<<<g2E, 256, 0, stream>>>(ei, flag, edg, 2 * E);
    hist_kernel<<<gE, 256, 0, stream>>>(dst, cnt, E);
    scan_kernel<<<1, 1024, 0, stream>>>(cnt, off, N);
    initcur_kernel<<<gN, 256, 0, stream>>>(off, cur, N);
    fillcsr_kernel<<<gE, 256, 0, stream>>>(dst, cur, csre, E);

    // Inputs
    build_xc0_kernel<<<gN, 256, 0, stream>>>(x, sdf, na, xc0, N);
    prep_bufs_kernel<<<gN, 256, 0, stream>>>(na, fy, bufA, bufB, N);

    // One FVnewConv layer, chunked over nodes
    auto run_layer = [&](const float* xc, int ldx, int C, int layer,
                         float* outbuf, bool final3) {
        int SC = 3 * C;
        for (int n0 = 0; n0 < N; n0 += chunk) {
            int rows = (N - n0 < chunk) ? (N - n0) : chunk;
            int gAg = (rows + 7) / 8;
            if (C == 7)
                aggr_kernel<1><<<gAg, 256, 0, stream>>>(xc, ldx, C, ea, src, off, csre,
                                                        win_[layer], bin_[layer], aggr, n0, rows);
            else
                aggr_kernel<7><<<gAg, 256, 0, stream>>>(xc, ldx, C, ea, src, off, csre,
                                                        win_[layer], bin_[layer], aggr, n0, rows);
            if (final3) {
                gemm_out3_kernel<<<rows, 256, 0, stream>>>(aggr, wout_[layer], bout_[layer],
                                                           (float*)d_out + (size_t)n0 * 3, SC);
            } else {
                dim3 g((rows + 127) / 128, 4);
                gemm_tanh_kernel<true><<<g, 256, 0, stream>>>(aggr, wout_[layer], bout_[layer],
                                                              outbuf + (size_t)n0 * 516,
                                                              rows, SC, 516, 3);
            }
        }
    };

    // p0: xc0[N,7] -> A      p1: A(+3) -> B       p2: B(+3) -> A
    // c0: A full    -> B     c1: B(+3) -> A       c2: A(+3) -> d_out
    run_layer(xc0,      7,   7,   0, bufA, false);
    run_layer(bufA + 3, 516, 513, 1, bufB, false);
    run_layer(bufB + 3, 516, 513, 2, bufA, false);
    run_layer(bufA,     516, 516, 3, bufB, false);
    run_layer(bufB + 3, 516, 513, 4, bufA, false);
    run_layer(bufA + 3, 516, 513, 5, nullptr, true);
}

// Round 12
// 13308.792 us; speedup vs baseline: 1.3075x; 1.3075x over previous
//
#include <hip/hip_runtime.h>
#include <math.h>

// Problem constants
#define NN 50000
#define NE 200000

// ---------------------------------------------------------------------------
// Init: flag=1 (assume int64 until disproven), cnt=0
// ---------------------------------------------------------------------------
__global__ __launch_bounds__(256) void initflag_kernel(int* __restrict__ flag,
                                                       int* __restrict__ cnt, int n) {
    int i = blockIdx.x * 256 + threadIdx.x;
    if (i == 0) flag[0] = 1;
    if (i < n) cnt[i] = 0;
}

// If ANY odd int32 slot among the first 4096 pairs is nonzero, data is int32.
__global__ __launch_bounds__(256) void sniff_kernel(const int* __restrict__ ei,
                                                    int* __restrict__ flag) {
    int t = threadIdx.x;
    int nz = 0;
    for (int i = t; i < 4096; i += 256) nz |= (ei[2 * i + 1] != 0);
    if (nz) flag[0] = 0;
}

// Normalize edge_index to int32 in edg[0..2E), clamped to [0, NN)
__global__ __launch_bounds__(256) void cvt_edges_kernel(const int* __restrict__ ei,
                                                        const int* __restrict__ flag,
                                                        int* __restrict__ edg, int n2e) {
    int i = blockIdx.x * 256 + threadIdx.x;
    if (i < n2e) {
        int v = flag[0] ? ei[2 * i] : ei[i];
        if ((unsigned)v >= (unsigned)NN) v = 0;
        edg[i] = v;
    }
}

// ---------------------------------------------------------------------------
// CSR build: histogram of dst, exclusive scan, counting-sort fill
// ---------------------------------------------------------------------------
__global__ __launch_bounds__(256) void hist_kernel(const int* __restrict__ dst,
                                                   int* __restrict__ cnt, int E) {
    int e = blockIdx.x * 256 + threadIdx.x;
    if (e < E) atomicAdd(&cnt[dst[e]], 1);
}

__global__ __launch_bounds__(1024) void scan_kernel(const int* __restrict__ cnt,
                                                    int* __restrict__ off, int n) {
    __shared__ int lds[1024];
    __shared__ int carry;
    int t = threadIdx.x;
    if (t == 0) { carry = 0; off[0] = 0; }
    __syncthreads();
    for (int base = 0; base < n; base += 1024) {
        int v = (base + t < n) ? cnt[base + t] : 0;
        lds[t] = v;
        __syncthreads();
        for (int s = 1; s < 1024; s <<= 1) {
            int x = (t >= s) ? lds[t - s] : 0;
            __syncthreads();
            lds[t] += x;
            __syncthreads();
        }
        int inc = lds[t] + carry;
        if (base + t < n) off[base + t + 1] = inc;
        __syncthreads();
        if (t == 1023) carry = inc;
        __syncthreads();
    }
}

__global__ __launch_bounds__(256) void initcur_kernel(const int* __restrict__ off,
                                                      int* __restrict__ cur, int n) {
    int i = blockIdx.x * 256 + threadIdx.x;
    if (i < n) cur[i] = off[i];
}

__global__ __launch_bounds__(256) void fillcsr_kernel(const int* __restrict__ dst,
                                                      int* __restrict__ cur,
                                                      int* __restrict__ csre, int E) {
    int e = blockIdx.x * 256 + threadIdx.x;
    if (e < E) {
        int p = atomicAdd(&cur[dst[e]], 1);
        csre[p] = e;
    }
}

// ---------------------------------------------------------------------------
// Input prep (buffer row layout [516]: [fy(3) | out(512) | na(1)])
// ---------------------------------------------------------------------------
__global__ __launch_bounds__(256) void build_xc0_kernel(const float* __restrict__ x,
                                                        const float* __restrict__ sdf,
                                                        const float* __restrict__ na,
                                                        float* __restrict__ xc0, int n) {
    int i = blockIdx.x * 256 + threadIdx.x;
    if (i >= n) return;
    float* r = xc0 + (size_t)i * 7;
    const float* xr = x + (size_t)i * 5;
    r[0] = xr[0]; r[1] = xr[1]; r[2] = xr[2]; r[3] = xr[3]; r[4] = xr[4];
    r[5] = sdf[i];
    r[6] = na[i];
}

__global__ __launch_bounds__(256) void prep_bufs_kernel(const float* __restrict__ na,
                                                        const float* __restrict__ fy,
                                                        float* __restrict__ bufA,
                                                        float* __restrict__ bufB, int n) {
    int i = blockIdx.x * 256 + threadIdx.x;
    if (i >= n) return;
    float v = na[i];
    bufA[(size_t)i * 516 + 515] = v;
    bufB[(size_t)i * 516 + 515] = v;
    bufA[(size_t)i * 516 + 0] = fy[(size_t)i * 3 + 0];
    bufA[(size_t)i * 516 + 1] = fy[(size_t)i * 3 + 1];
    bufA[(size_t)i * 516 + 2] = fy[(size_t)i * 3 + 2];
}

// ---------------------------------------------------------------------------
// K-strip aggregation: Astrip[n, j] = sum_{e:dst=n} relu(ea[e]·win[kbase+j]+bin)
//                                      * xc[src[e], (kbase+j)/3],  j in [0,KSs)
// ONE NODE PER WAVE (4 waves/block, NPW=4 nodes serial per wave) -> 32
// independent latency chains per CU at 8 blocks/CU (vs 8 for block-lockstep).
// Lane l covers cols j = l + 64*k, k < KC (KC<=5 -> wr fits in regs, no spill).
// No barriers in this kernel: early return per-wave is safe.
// ---------------------------------------------------------------------------
template <int KC>
__global__ __launch_bounds__(256) void aggr_strip_kernel(
        const float* __restrict__ xc, int ldx,
        const float* __restrict__ ea, const int* __restrict__ src,
        const int* __restrict__ off, const int* __restrict__ csre,
        const float* __restrict__ win, const float* __restrict__ bin,
        float* __restrict__ Astrip, int asld, int kbase, int KSs, int nNodes) {
    const int NPW = 4;
    int t = threadIdx.x;
    int lane = t & 63, wid = t >> 6;
    float wr[KC][6], br[KC];
    int ci[KC]; bool ok[KC];
#pragma unroll
    for (int k = 0; k < KC; ++k) {
        int j = lane + 64 * k;
        ok[k] = (j < KSs);
        int c = kbase + (ok[k] ? j : 0);
        ci[k] = c / 3;
        const float* w = win + (size_t)c * 6;
        br[k] = ok[k] ? bin[c] : 0.f;
#pragma unroll
        for (int q = 0; q < 6; ++q) wr[k][q] = ok[k] ? w[q] : 0.f;
    }
    int node = (blockIdx.x * 4 + wid) * NPW;
    for (int nn = 0; nn < NPW; ++nn, ++node) {
        if (node >= nNodes) return;
        float acc[KC];
#pragma unroll
        for (int k = 0; k < KC; ++k) acc[k] = 0.f;
        int e1 = off[node + 1];
        for (int ie = off[node]; ie < e1; ++ie) {
            int e = csre[ie];
            const float* er = ea + (size_t)e * 6;
            float a0 = er[0], a1 = er[1], a2 = er[2];
            float a3 = er[3], a4 = er[4], a5 = er[5];
            const float* xr = xc + (size_t)src[e] * ldx;
#pragma unroll
            for (int k = 0; k < KC; ++k) {
                float sc = br[k];
                sc = fmaf(a0, wr[k][0], sc);
                sc = fmaf(a1, wr[k][1], sc);
                sc = fmaf(a2, wr[k][2], sc);
                sc = fmaf(a3, wr[k][3], sc);
                sc = fmaf(a4, wr[k][4], sc);
                sc = fmaf(a5, wr[k][5], sc);
                sc = fmaxf(sc, 0.f);
                acc[k] = fmaf(sc, xr[ci[k]], acc[k]);
            }
        }
        float* ar = Astrip + (size_t)node * asld;
#pragma unroll
        for (int k = 0; k < KC; ++k)
            if (ok[k]) ar[lane + 64 * k] = acc[k];
    }
}

// ---------------------------------------------------------------------------
// Strip GEMM with accumulation: C[m,n] (+)= A[m,:K]·W[n,kbase:kbase+K]
// doInit: no C read (first strip). doLast: apply relu(tanh(.+bias)).
// Full-N grid every strip: (M/128) x 4 = 1564 blocks -> ~6 resident blocks/CU.
// BM=BN=128, BK=16, 256 thr, 8x8 microtile; LDS [16][132] transposed+padded.
// ---------------------------------------------------------------------------
__global__ __launch_bounds__(256) void gemm_strip_kernel(
        const float* __restrict__ A, int ald,
        const float* __restrict__ W, int wld, int kbase, int K,
        const float* __restrict__ bias,
        float* __restrict__ C, int cld, int M, int doInit, int doLast) {
    __shared__ float As[16][132];
    __shared__ float Bs[16][132];
    int t = threadIdx.x;
    int m0 = blockIdx.x * 128;
    int n0 = blockIdx.y * 128;
    int tx = t & 15, ty = t >> 4;
    int kk0 = t & 15;
    int r0 = t >> 4;
    float acc[8][8];
#pragma unroll
    for (int i = 0; i < 8; ++i)
#pragma unroll
        for (int j = 0; j < 8; ++j) acc[i][j] = 0.f;

    for (int k0 = 0; k0 < K; k0 += 16) {
        int gk = k0 + kk0;
        bool kok = (gk < K);
#pragma unroll
        for (int j = 0; j < 8; ++j) {
            int r = r0 + 16 * j;
            int gm = m0 + r;
            As[kk0][r] = (kok && gm < M) ? A[(size_t)gm * ald + gk] : 0.f;
            int gn = n0 + r;  // < 512 given grid.y = 4
            Bs[kk0][r] = kok ? W[(size_t)gn * wld + kbase + gk] : 0.f;
        }
        __syncthreads();
#pragma unroll
        for (int kk = 0; kk < 16; ++kk) {
            float a[8], b[8];
            *(float4*)&a[0] = *(const float4*)&As[kk][ty * 8];
            *(float4*)&a[4] = *(const float4*)&As[kk][ty * 8 + 4];
            *(float4*)&b[0] = *(const float4*)&Bs[kk][tx * 8];
            *(float4*)&b[4] = *(const float4*)&Bs[kk][tx * 8 + 4];
#pragma unroll
            for (int i = 0; i < 8; ++i)
#pragma unroll
                for (int j = 0; j < 8; ++j) acc[i][j] = fmaf(a[i], b[j], acc[i][j]);
        }
        __syncthreads();
    }

#pragma unroll
    for (int i = 0; i < 8; ++i) {
        int gm = m0 + ty * 8 + i;
        if (gm < M) {
#pragma unroll
            for (int j = 0; j < 8; ++j) {
                int gn = n0 + tx * 8 + j;
                float v = acc[i][j];
                if (!doInit) v += C[(size_t)gm * cld + gn];
                if (doLast) {
                    v = tanhf(v + bias[gn]);
                    v = fmaxf(v, 0.f);   // all 512-out layers are relu'd
                }
                C[(size_t)gm * cld + gn] = v;
            }
        }
    }
}

// ---------------------------------------------------------------------------
// Final layer (out=3) strip dot with accumulation into d_out
// ---------------------------------------------------------------------------
__global__ __launch_bounds__(256) void out3_strip_kernel(
        const float* __restrict__ A, int ald, int kbase, int K,
        const float* __restrict__ W, int wld,
        const float* __restrict__ bias, float* __restrict__ out,
        int doInit, int doLast) {
    int n = blockIdx.x;
    int t = threadIdx.x;
    const float* ar = A + (size_t)n * ald;
    const float* w0 = W + kbase;
    const float* w1 = W + (size_t)wld + kbase;
    const float* w2 = W + 2 * (size_t)wld + kbase;
    float s0 = 0.f, s1 = 0.f, s2 = 0.f;
    for (int k = t; k < K; k += 256) {
        float a = ar[k];
        s0 = fmaf(a, w0[k], s0);
        s1 = fmaf(a, w1[k], s1);
        s2 = fmaf(a, w2[k], s2);
    }
#pragma unroll
    for (int d = 32; d >= 1; d >>= 1) {
        s0 += __shfl_down(s0, d, 64);
        s1 += __shfl_down(s1, d, 64);
        s2 += __shfl_down(s2, d, 64);
    }
    __shared__ float red[4][3];
    int lane = t & 63, w = t >> 6;
    if (lane == 0) { red[w][0] = s0; red[w][1] = s1; red[w][2] = s2; }
    __syncthreads();
    if (t == 0) {
        float r0 = red[0][0] + red[1][0] + red[2][0] + red[3][0];
        float r1 = red[0][1] + red[1][1] + red[2][1] + red[3][1];
        float r2 = red[0][2] + red[1][2] + red[2][2] + red[3][2];
        float p0 = doInit ? 0.f : out[(size_t)n * 3 + 0];
        float p1 = doInit ? 0.f : out[(size_t)n * 3 + 1];
        float p2 = doInit ? 0.f : out[(size_t)n * 3 + 2];
        p0 += r0; p1 += r1; p2 += r2;
        if (doLast) {
            p0 = tanhf(p0 + bias[0]);
            p1 = tanhf(p1 + bias[1]);
            p2 = tanhf(p2 + bias[2]);
        }
        out[(size_t)n * 3 + 0] = p0;
        out[(size_t)n * 3 + 1] = p1;
        out[(size_t)n * 3 + 2] = p2;
    }
}

__global__ __launch_bounds__(256) void zero_out_kernel(float* __restrict__ o, int n) {
    int i = blockIdx.x * 256 + threadIdx.x;
    if (i < n) o[i] = 0.f;
}

// ---------------------------------------------------------------------------
extern "C" void kernel_launch(void* const* d_in, const int* in_sizes, int n_in,
                              void* d_out, int out_size, void* d_ws, size_t ws_size,
                              hipStream_t stream) {
    const int N = NN, E = NE;
    const float* x   = (const float*)d_in[0];
    const float* sdf = (const float*)d_in[1];
    const float* na  = (const float*)d_in[2];
    const float* ea  = (const float*)d_in[3];
    const float* fy  = (const float*)d_in[4];
    const int*   ei  = (const int*)d_in[5];
    const float* win_[6];
    const float* bin_[6];
    const float* wout_[6];
    const float* bout_[6];
    for (int l = 0; l < 6; ++l) {
        win_[l]  = (const float*)d_in[6 + 4 * l + 0];
        bin_[l]  = (const float*)d_in[6 + 4 * l + 1];
        wout_[l] = (const float*)d_in[6 + 4 * l + 2];
        bout_[l] = (const float*)d_in[6 + 4 * l + 3];
    }

    // ---- ws layout: fixed bufs + ints; K-strip buffer takes the remainder ----
    char* base = (char*)d_ws;
    float* bufA = (float*)base;
    float* bufB = bufA + (size_t)N * 516;
    float* xc0  = bufB + (size_t)N * 516;
    int* off  = (int*)(xc0 + (size_t)N * 7);
    int* cnt  = off + (N + 1);
    int* cur  = cnt + N;
    int* csre = cur + N;
    int* edg  = csre + E;
    int* flag = edg + 2 * E;
    char* as_base = (char*)(flag + 1);
    as_base += (64 - ((size_t)(as_base - base) & 63)) & 63;
    float* Astrip = (float*)as_base;
    size_t used = (size_t)(as_base - base);

    // Strip width: ws-adaptive, capped at 320 (KC<=5 keeps aggr weights in regs)
    int KSW = 0;
    if (ws_size > used) {
        size_t av_floats = (ws_size - used) / 4;
        size_t w = av_floats / (size_t)N;
        if (w > 320) w = 320;
        KSW = (int)(w & ~(size_t)3);   // multiple of 4
    }
    if (KSW < 8) {   // ws far too small — loud, safe failure
        zero_out_kernel<<<(out_size + 255) / 256, 256, 0, stream>>>((float*)d_out, out_size);
        return;
    }

    const int* src = edg;
    const int* dst = edg + E;
    int gE = (E + 255) / 256;
    int gN = (N + 255) / 256;
    int g2E = (2 * E + 255) / 256;

    // Edge normalize + CSR build
    initflag_kernel<<<gN, 256, 0, stream>>>(flag, cnt, N);
    sniff_kernel<<<1, 256, 0, stream>>>(ei, flag);
    cvt_edges_kernel<<<g2E, 256, 0, stream>>>(ei, flag, edg, 2 * E);
    hist_kernel<<<gE, 256, 0, stream>>>(dst, cnt, E);
    scan_kernel<<<1, 1024, 0, stream>>>(cnt, off, N);
    initcur_kernel<<<gN, 256, 0, stream>>>(off, cur, N);
    fillcsr_kernel<<<gE, 256, 0, stream>>>(dst, cur, csre, E);

    // Inputs
    build_xc0_kernel<<<gN, 256, 0, stream>>>(x, sdf, na, xc0, N);
    prep_bufs_kernel<<<gN, 256, 0, stream>>>(na, fy, bufA, bufB, N);

    int gA = (N + 15) / 16;            // 4 waves * 4 nodes per block
    dim3 gG((N + 127) / 128, 4);       // full-N GEMM grid, every strip

    // One FVnewConv layer as K-strips: aggr_strip -> gemm_strip(accumulate)
    auto run_layer = [&](const float* xcp, int ldx, int C, int layer,
                         float* outC, bool final3) {
        int SC = 3 * C;
        int kbase = 0;
        while (kbase < SC) {
            int KSs = SC - kbase;
            if (KSs > KSW) KSs = KSW;
            int doInit = (kbase == 0) ? 1 : 0;
            int doLast = (kbase + KSs >= SC) ? 1 : 0;
            int KC = (KSs + 63) / 64;
            switch (KC) {
                case 1: aggr_strip_kernel<1><<<gA, 256, 0, stream>>>(xcp, ldx, ea, src, off, csre,
                            win_[layer], bin_[layer], Astrip, KSW, kbase, KSs, N); break;
                case 2: aggr_strip_kernel<2><<<gA, 256, 0, stream>>>(xcp, ldx, ea, src, off, csre,
                            win_[layer], bin_[layer], Astrip, KSW, kbase, KSs, N); break;
                case 3: aggr_strip_kernel<3><<<gA, 256, 0, stream>>>(xcp, ldx, ea, src, off, csre,
                            win_[layer], bin_[layer], Astrip, KSW, kbase, KSs, N); break;
                case 4: aggr_strip_kernel<4><<<gA, 256, 0, stream>>>(xcp, ldx, ea, src, off, csre,
                            win_[layer], bin_[layer], Astrip, KSW, kbase, KSs, N); break;
                default: aggr_strip_kernel<5><<<gA, 256, 0, stream>>>(xcp, ldx, ea, src, off, csre,
                            win_[layer], bin_[layer], Astrip, KSW, kbase, KSs, N); break;
            }
            if (final3) {
                out3_strip_kernel<<<N, 256, 0, stream>>>(Astrip, KSW, kbase, KSs,
                        wout_[layer], SC, bout_[layer], (float*)d_out, doInit, doLast);
            } else {
                gemm_strip_kernel<<<gG, 256, 0, stream>>>(Astrip, KSW,
                        wout_[layer], SC, kbase, KSs, bout_[layer],
                        outC, 516, N, doInit, doLast);
            }
            kbase += KSs;
        }
    };

    // p0: xc0[N,7] -> A      p1: A(+3) -> B       p2: B(+3) -> A
    // c0: A full    -> B     c1: B(+3) -> A       c2: A(+3) -> d_out
    run_layer(xc0,      7,   7,   0, bufA + 3, false);
    run_layer(bufA + 3, 516, 513, 1, bufB + 3, false);
    run_layer(bufB + 3, 516, 513, 2, bufA + 3, false);
    run_layer(bufA,     516, 516, 3, bufB + 3, false);
    run_layer(bufB + 3, 516, 513, 4, bufA + 3, false);
    run_layer(bufA + 3, 516, 513, 5, nullptr, true);
}

// Round 15
// 7764.561 us; speedup vs baseline: 2.2412x; 1.7140x over previous
//
#include <hip/hip_runtime.h>
#include <math.h>

#define NN 50000
#define NE 200000

typedef __attribute__((ext_vector_type(8))) short sh8;     // 8 bf16 (4 VGPRs)
typedef __attribute__((ext_vector_type(4))) float f32x4;   // MFMA acc

__device__ __forceinline__ unsigned short f2bf(float x) {  // RNE fp32->bf16
    union { float f; unsigned u; } v; v.f = x;
    return (unsigned short)((v.u + 0x7FFFu + ((v.u >> 16) & 1u)) >> 16);
}
__device__ __forceinline__ float bf2f(unsigned short h) {
    union { unsigned u; float f; } v; v.u = ((unsigned)h) << 16;
    return v.f;
}

// ---------------------------------------------------------------------------
// Edge normalize + CSR build
// ---------------------------------------------------------------------------
__global__ __launch_bounds__(256) void initflag_kernel(int* __restrict__ flag,
                                                       int* __restrict__ cnt, int n) {
    int i = blockIdx.x * 256 + threadIdx.x;
    if (i == 0) flag[0] = 1;
    if (i < n) cnt[i] = 0;
}

__global__ __launch_bounds__(256) void sniff_kernel(const int* __restrict__ ei,
                                                    int* __restrict__ flag) {
    int t = threadIdx.x;
    int nz = 0;
    for (int i = t; i < 4096; i += 256) nz |= (ei[2 * i + 1] != 0);
    if (nz) flag[0] = 0;
}

__global__ __launch_bounds__(256) void cvt_edges_kernel(const int* __restrict__ ei,
                                                        const int* __restrict__ flag,
                                                        int* __restrict__ edg, int n2e) {
    int i = blockIdx.x * 256 + threadIdx.x;
    if (i < n2e) {
        int v = flag[0] ? ei[2 * i] : ei[i];
        if ((unsigned)v >= (unsigned)NN) v = 0;
        edg[i] = v;
    }
}

__global__ __launch_bounds__(256) void hist_kernel(const int* __restrict__ dst,
                                                   int* __restrict__ cnt, int E) {
    int e = blockIdx.x * 256 + threadIdx.x;
    if (e < E) atomicAdd(&cnt[dst[e]], 1);
}

__global__ __launch_bounds__(1024) void scan_kernel(const int* __restrict__ cnt,
                                                    int* __restrict__ off, int n) {
    __shared__ int lds[1024];
    __shared__ int carry;
    int t = threadIdx.x;
    if (t == 0) { carry = 0; off[0] = 0; }
    __syncthreads();
    for (int base = 0; base < n; base += 1024) {
        int v = (base + t < n) ? cnt[base + t] : 0;
        lds[t] = v;
        __syncthreads();
        for (int s = 1; s < 1024; s <<= 1) {
            int x = (t >= s) ? lds[t - s] : 0;
            __syncthreads();
            lds[t] += x;
            __syncthreads();
        }
        int inc = lds[t] + carry;
        if (base + t < n) off[base + t + 1] = inc;
        __syncthreads();
        if (t == 1023) carry = inc;
        __syncthreads();
    }
}

__global__ __launch_bounds__(256) void initcur_kernel(const int* __restrict__ off,
                                                      int* __restrict__ cur, int n) {
    int i = blockIdx.x * 256 + threadIdx.x;
    if (i < n) cur[i] = off[i];
}

__global__ __launch_bounds__(256) void fillcsr_kernel(const int* __restrict__ dst,
                                                      int* __restrict__ cur,
                                                      int* __restrict__ csre, int E) {
    int e = blockIdx.x * 256 + threadIdx.x;
    if (e < E) {
        int p = atomicAdd(&cur[dst[e]], 1);
        csre[p] = e;
    }
}

// ---------------------------------------------------------------------------
// Input prep (buffer row layout [516]: [fy(3) | out(512) | na(1)])
// ---------------------------------------------------------------------------
__global__ __launch_bounds__(256) void build_xc0_kernel(const float* __restrict__ x,
                                                        const float* __restrict__ sdf,
                                                        const float* __restrict__ na,
                                                        float* __restrict__ xc0, int n) {
    int i = blockIdx.x * 256 + threadIdx.x;
    if (i >= n) return;
    float* r = xc0 + (size_t)i * 7;
    const float* xr = x + (size_t)i * 5;
    r[0] = xr[0]; r[1] = xr[1]; r[2] = xr[2]; r[3] = xr[3]; r[4] = xr[4];
    r[5] = sdf[i];
    r[6] = na[i];
}

__global__ __launch_bounds__(256) void prep_bufs_kernel(const float* __restrict__ na,
                                                        const float* __restrict__ fy,
                                                        float* __restrict__ bufA,
                                                        float* __restrict__ bufB, int n) {
    int i = blockIdx.x * 256 + threadIdx.x;
    if (i >= n) return;
    float v = na[i];
    bufA[(size_t)i * 516 + 515] = v;
    bufB[(size_t)i * 516 + 515] = v;
    bufA[(size_t)i * 516 + 0] = fy[(size_t)i * 3 + 0];
    bufA[(size_t)i * 516 + 1] = fy[(size_t)i * 3 + 1];
    bufA[(size_t)i * 516 + 2] = fy[(size_t)i * 3 + 2];
}

// ---------------------------------------------------------------------------
// W split: Wh/Wl bf16 planes, rows padded to SCpad (zero fill)
// ---------------------------------------------------------------------------
__global__ __launch_bounds__(256) void wsplit_kernel(const float* __restrict__ W,
                                                     unsigned short* __restrict__ Wh,
                                                     unsigned short* __restrict__ Wl,
                                                     int rows, int SC, int SCpad) {
    int total = rows * SCpad;
    for (int i = blockIdx.x * 256 + threadIdx.x; i < total; i += gridDim.x * 256) {
        int row = i / SCpad, k = i - row * SCpad;
        float v = (k < SC) ? W[(size_t)row * SC + k] : 0.f;
        unsigned short h = f2bf(v);
        Wh[i] = h;
        Wl[i] = f2bf(v - bf2f(h));
    }
}

// ---------------------------------------------------------------------------
// K-strip aggregation -> split bf16 planes Ah/Al (strip-local columns).
// One node per wave (4 waves/block, 4 nodes serial/wave). KC <= 4.
// Zero-fills cols [KSs, zfill) so the GEMM can stage rounded-to-32 K.
// ---------------------------------------------------------------------------
template <int KC>
__global__ __launch_bounds__(256) void aggr_strip_kernel(
        const float* __restrict__ xc, int ldx,
        const float* __restrict__ ea, const int* __restrict__ src,
        const int* __restrict__ off, const int* __restrict__ csre,
        const float* __restrict__ win, const float* __restrict__ bin,
        unsigned short* __restrict__ Ah, unsigned short* __restrict__ Al,
        int asld, int kbase, int KSs, int zfill, int nNodes) {
    const int NPW = 4;
    int t = threadIdx.x;
    int lane = t & 63, wid = t >> 6;
    float wr[KC][6], br[KC];
    int ci[KC]; bool ok[KC];
#pragma unroll
    for (int k = 0; k < KC; ++k) {
        int j = lane + 64 * k;
        ok[k] = (j < KSs);
        int c = kbase + (ok[k] ? j : 0);
        ci[k] = c / 3;
        const float* w = win + (size_t)c * 6;
        br[k] = ok[k] ? bin[c] : 0.f;
#pragma unroll
        for (int q = 0; q < 6; ++q) wr[k][q] = ok[k] ? w[q] : 0.f;
    }
    int node = (blockIdx.x * 4 + wid) * NPW;
    for (int nn = 0; nn < NPW; ++nn, ++node) {
        if (node >= nNodes) return;
        float acc[KC];
#pragma unroll
        for (int k = 0; k < KC; ++k) acc[k] = 0.f;
        int e1 = off[node + 1];
        for (int ie = off[node]; ie < e1; ++ie) {
            int e = csre[ie];
            const float* er = ea + (size_t)e * 6;
            float a0 = er[0], a1 = er[1], a2 = er[2];
            float a3 = er[3], a4 = er[4], a5 = er[5];
            const float* xr = xc + (size_t)src[e] * ldx;
#pragma unroll
            for (int k = 0; k < KC; ++k) {
                float sc = br[k];
                sc = fmaf(a0, wr[k][0], sc);
                sc = fmaf(a1, wr[k][1], sc);
                sc = fmaf(a2, wr[k][2], sc);
                sc = fmaf(a3, wr[k][3], sc);
                sc = fmaf(a4, wr[k][4], sc);
                sc = fmaf(a5, wr[k][5], sc);
                sc = fmaxf(sc, 0.f);
                acc[k] = fmaf(sc, xr[ci[k]], acc[k]);
            }
        }
        unsigned short* ah = Ah + (size_t)node * asld;
        unsigned short* al = Al + (size_t)node * asld;
#pragma unroll
        for (int k = 0; k < KC; ++k) {
            if (ok[k]) {
                int j = lane + 64 * k;
                unsigned short h = f2bf(acc[k]);
                ah[j] = h;
                al[j] = f2bf(acc[k] - bf2f(h));
            }
        }
        for (int j = KSs + lane; j < zfill; j += 64) { ah[j] = 0; al[j] = 0; }
    }
}

// ---------------------------------------------------------------------------
// Split-bf16 MFMA strip GEMM: C[m,n] (+)= A[m,:]·W[n,:] over this K-strip.
// BM=128, BN=64, BK=32 (one mfma_f32_16x16x32_bf16 K-step per stage).
// 4 waves: wave w owns rows [w*32, w*32+32) x 64 cols = 2x4 16x16 frags.
// 4-term split: (Ah+Al)(Wh+Wl) -> fp32-grade accuracy; fp32 accumulate.
// LDS rows padded to 40 ushorts (80 B, 16B-divisible) -> 2-way aliasing only.
// C/D layout (HW-verified m89/m91): col=lane&15, row=(lane>>4)*4+reg.
// ---------------------------------------------------------------------------
__global__ __launch_bounds__(256) void gemm_mfma_kernel(
        const unsigned short* __restrict__ Ah, const unsigned short* __restrict__ Al, int ald,
        const unsigned short* __restrict__ Wh, const unsigned short* __restrict__ Wl, int wld,
        int kbase, int nk,
        const float* __restrict__ bias,
        float* __restrict__ C, int cld, int M, int doInit, int doLast) {
    __shared__ __align__(16) unsigned short lAh[128 * 40];
    __shared__ __align__(16) unsigned short lAl[128 * 40];
    __shared__ __align__(16) unsigned short lWh[64 * 40];
    __shared__ __align__(16) unsigned short lWl[64 * 40];
    int t = threadIdx.x;
    int m0 = blockIdx.x * 128;
    int n0 = blockIdx.y * 64;
    int lane = t & 63, w = t >> 6;
    f32x4 acc[2][4];
#pragma unroll
    for (int mi = 0; mi < 2; ++mi)
#pragma unroll
        for (int ni = 0; ni < 4; ++ni) acc[mi][ni] = (f32x4)(0.f);

    for (int ks = 0; ks < nk; ++ks) {
        int klocA = ks * 32;         // A is strip-local
        int kgW = kbase + ks * 32;   // W is layer-global (padded rows)
        // stage A planes: 128 rows x 32 bf16, 16B segs, 512 segs -> 2 iters
        for (int s = t; s < 512; s += 256) {
            int row = s >> 2, sg = s & 3;
            int gm = m0 + row;
            uint4 vh = make_uint4(0, 0, 0, 0), vl = make_uint4(0, 0, 0, 0);
            if (gm < M) {
                vh = *(const uint4*)&Ah[(size_t)gm * ald + klocA + sg * 8];
                vl = *(const uint4*)&Al[(size_t)gm * ald + klocA + sg * 8];
            }
            *(uint4*)&lAh[row * 40 + sg * 8] = vh;
            *(uint4*)&lAl[row * 40 + sg * 8] = vl;
        }
        // stage W planes: 64 rows x 32 bf16, 256 segs -> 1 iter
        {
            int row = t >> 2, sg = t & 3;
            int gn = n0 + row;   // < 512 by grid.y = 8
            *(uint4*)&lWh[row * 40 + sg * 8] =
                *(const uint4*)&Wh[(size_t)gn * wld + kgW + sg * 8];
            *(uint4*)&lWl[row * 40 + sg * 8] =
                *(const uint4*)&Wl[(size_t)gn * wld + kgW + sg * 8];
        }
        __syncthreads();
        sh8 fah[2], fal[2];
#pragma unroll
        for (int mi = 0; mi < 2; ++mi) {
            int row = w * 32 + mi * 16 + (lane & 15);
            int idx = row * 40 + (lane >> 4) * 8;
            fah[mi] = *(const sh8*)&lAh[idx];
            fal[mi] = *(const sh8*)&lAl[idx];
        }
#pragma unroll
        for (int ni = 0; ni < 4; ++ni) {
            int rw = ni * 16 + (lane & 15);
            int idx = rw * 40 + (lane >> 4) * 8;
            sh8 fwh = *(const sh8*)&lWh[idx];
            sh8 fwl = *(const sh8*)&lWl[idx];
#pragma unroll
            for (int mi = 0; mi < 2; ++mi) {
                acc[mi][ni] = __builtin_amdgcn_mfma_f32_16x16x32_bf16(fah[mi], fwh, acc[mi][ni], 0, 0, 0);
                acc[mi][ni] = __builtin_amdgcn_mfma_f32_16x16x32_bf16(fal[mi], fwh, acc[mi][ni], 0, 0, 0);
                acc[mi][ni] = __builtin_amdgcn_mfma_f32_16x16x32_bf16(fah[mi], fwl, acc[mi][ni], 0, 0, 0);
                acc[mi][ni] = __builtin_amdgcn_mfma_f32_16x16x32_bf16(fal[mi], fwl, acc[mi][ni], 0, 0, 0);
            }
        }
        __syncthreads();
    }
    // epilogue: C/D frag -> global, accumulate across strips, act on last
#pragma unroll
    for (int mi = 0; mi < 2; ++mi) {
#pragma unroll
        for (int r = 0; r < 4; ++r) {
            int gm = m0 + w * 32 + mi * 16 + (lane >> 4) * 4 + r;
            if (gm < M) {
#pragma unroll
                for (int ni = 0; ni < 4; ++ni) {
                    int gn = n0 + ni * 16 + (lane & 15);
                    float v = acc[mi][ni][r];
                    if (!doInit) v += C[(size_t)gm * cld + gn];
                    if (doLast) {
                        v = tanhf(v + bias[gn]);
                        v = fmaxf(v, 0.f);
                    }
                    C[(size_t)gm * cld + gn] = v;
                }
            }
        }
    }
}

// ---------------------------------------------------------------------------
// Final layer (out=3): strip dot from split-bf16 A, fp32 W, accumulate d_out
// ---------------------------------------------------------------------------
__global__ __launch_bounds__(256) void out3_strip_kernel(
        const unsigned short* __restrict__ Ah, const unsigned short* __restrict__ Al,
        int ald, int kbase, int K,
        const float* __restrict__ W, int wld,
        const float* __restrict__ bias, float* __restrict__ out,
        int doInit, int doLast) {
    int n = blockIdx.x;
    int t = threadIdx.x;
    const unsigned short* ah = Ah + (size_t)n * ald;
    const unsigned short* al = Al + (size_t)n * ald;
    const float* w0 = W + kbase;
    const float* w1 = W + (size_t)wld + kbase;
    const float* w2 = W + 2 * (size_t)wld + kbase;
    float s0 = 0.f, s1 = 0.f, s2 = 0.f;
    for (int k = t; k < K; k += 256) {
        float a = bf2f(ah[k]) + bf2f(al[k]);
        s0 = fmaf(a, w0[k], s0);
        s1 = fmaf(a, w1[k], s1);
        s2 = fmaf(a, w2[k], s2);
    }
#pragma unroll
    for (int d = 32; d >= 1; d >>= 1) {
        s0 += __shfl_down(s0, d, 64);
        s1 += __shfl_down(s1, d, 64);
        s2 += __shfl_down(s2, d, 64);
    }
    __shared__ float red[4][3];
    int lane = t & 63, w = t >> 6;
    if (lane == 0) { red[w][0] = s0; red[w][1] = s1; red[w][2] = s2; }
    __syncthreads();
    if (t == 0) {
        float r0 = red[0][0] + red[1][0] + red[2][0] + red[3][0];
        float r1 = red[0][1] + red[1][1] + red[2][1] + red[3][1];
        float r2 = red[0][2] + red[1][2] + red[2][2] + red[3][2];
        float p0 = doInit ? 0.f : out[(size_t)n * 3 + 0];
        float p1 = doInit ? 0.f : out[(size_t)n * 3 + 1];
        float p2 = doInit ? 0.f : out[(size_t)n * 3 + 2];
        p0 += r0; p1 += r1; p2 += r2;
        if (doLast) {
            p0 = tanhf(p0 + bias[0]);
            p1 = tanhf(p1 + bias[1]);
            p2 = tanhf(p2 + bias[2]);
        }
        out[(size_t)n * 3 + 0] = p0;
        out[(size_t)n * 3 + 1] = p1;
        out[(size_t)n * 3 + 2] = p2;
    }
}

__global__ __launch_bounds__(256) void zero_out_kernel(float* __restrict__ o, int n) {
    int i = blockIdx.x * 256 + threadIdx.x;
    if (i < n) o[i] = 0.f;
}

// ---------------------------------------------------------------------------
extern "C" void kernel_launch(void* const* d_in, const int* in_sizes, int n_in,
                              void* d_out, int out_size, void* d_ws, size_t ws_size,
                              hipStream_t stream) {
    const int N = NN, E = NE;
    const float* x   = (const float*)d_in[0];
    const float* sdf = (const float*)d_in[1];
    const float* na  = (const float*)d_in[2];
    const float* ea  = (const float*)d_in[3];
    const float* fy  = (const float*)d_in[4];
    const int*   ei  = (const int*)d_in[5];
    const float* win_[6];
    const float* bin_[6];
    const float* wout_[6];
    const float* bout_[6];
    for (int l = 0; l < 6; ++l) {
        win_[l]  = (const float*)d_in[6 + 4 * l + 0];
        bin_[l]  = (const float*)d_in[6 + 4 * l + 1];
        wout_[l] = (const float*)d_in[6 + 4 * l + 2];
        bout_[l] = (const float*)d_in[6 + 4 * l + 3];
    }

    const int SCs[6]  = {21, 1539, 1539, 1548, 1539, 1539};
    const int outc[6] = {512, 512, 512, 512, 512, 3};
    int SCp[6];
    for (int l = 0; l < 6; ++l) SCp[l] = (SCs[l] + 31) & ~31;

    // ---- ws layout ----
    char* base = (char*)d_ws;
    float* bufA = (float*)base;
    float* bufB = bufA + (size_t)N * 516;
    float* xc0  = bufB + (size_t)N * 516;
    int* off  = (int*)(xc0 + (size_t)N * 7);
    int* cnt  = off + (N + 1);
    int* cur  = cnt + N;
    int* csre = cur + N;
    int* edg  = csre + E;
    int* flag = edg + 2 * E;
    char* p = (char*)(flag + 1);
    p += (64 - ((size_t)(p - base) & 63)) & 63;
    unsigned short* Wh_[6];
    unsigned short* Wl_[6];
    for (int l = 0; l < 6; ++l) {
        Wh_[l] = (unsigned short*)p; p += (size_t)outc[l] * SCp[l] * 2;
        Wl_[l] = (unsigned short*)p; p += (size_t)outc[l] * SCp[l] * 2;
    }
    p += (64 - ((size_t)(p - base) & 63)) & 63;
    size_t used = (size_t)(p - base);

    int KSW = 0;
    if (ws_size > used) {
        size_t wcols = (ws_size - used) / ((size_t)4 * N);   // 2 planes x 2B per col
        if (wcols > 224) wcols = 224;
        KSW = (int)(wcols & ~(size_t)31);
    }
    if (KSW < 32) {   // ws far too small — loud, safe failure
        zero_out_kernel<<<(out_size + 255) / 256, 256, 0, stream>>>((float*)d_out, out_size);
        return;
    }
    unsigned short* AstripH = (unsigned short*)p;
    unsigned short* AstripL = AstripH + (size_t)N * KSW;

    const int* src = edg;
    const int* dst = edg + E;
    int gE = (E + 255) / 256;
    int gN = (N + 255) / 256;
    int g2E = (2 * E + 255) / 256;

    // Edge normalize + CSR build
    initflag_kernel<<<gN, 256, 0, stream>>>(flag, cnt, N);
    sniff_kernel<<<1, 256, 0, stream>>>(ei, flag);
    cvt_edges_kernel<<<g2E, 256, 0, stream>>>(ei, flag, edg, 2 * E);
    hist_kernel<<<gE, 256, 0, stream>>>(dst, cnt, E);
    scan_kernel<<<1, 1024, 0, stream>>>(cnt, off, N);
    initcur_kernel<<<gN, 256, 0, stream>>>(off, cur, N);
    fillcsr_kernel<<<gE, 256, 0, stream>>>(dst, cur, csre, E);

    // Inputs + weight splits
    build_xc0_kernel<<<gN, 256, 0, stream>>>(x, sdf, na, xc0, N);
    prep_bufs_kernel<<<gN, 256, 0, stream>>>(na, fy, bufA, bufB, N);
    for (int l = 0; l < 6; ++l) {
        int total = outc[l] * SCp[l];
        int g = (total + 255) / 256;
        if (g > 2048) g = 2048;
        wsplit_kernel<<<g, 256, 0, stream>>>(wout_[l], Wh_[l], Wl_[l], outc[l], SCs[l], SCp[l]);
    }

    int gA = (N + 15) / 16;              // aggr: 4 waves x 4 nodes per block
    dim3 gG((N + 127) / 128, 8);         // MFMA GEMM: BM=128, BN=64

    auto run_layer = [&](const float* xcp, int ldx, int C, int layer,
                         float* outC, bool final3) {
        int SC = 3 * C;
        int kbase = 0;
        while (kbase < SC) {
            int KSs = SC - kbase;
            if (KSs > KSW) KSs = KSW;
            int zfill = (KSs + 31) & ~31;
            if (zfill > KSW) zfill = KSW;
            int doInit = (kbase == 0) ? 1 : 0;
            int doLast = (kbase + KSs >= SC) ? 1 : 0;
            int KC = (KSs + 63) / 64;   // <= 4 (KSW <= 224)
            switch (KC) {
                case 1: aggr_strip_kernel<1><<<gA, 256, 0, stream>>>(xcp, ldx, ea, src, off, csre,
                            win_[layer], bin_[layer], AstripH, AstripL, KSW, kbase, KSs, zfill, N); break;
                case 2: aggr_strip_kernel<2><<<gA, 256, 0, stream>>>(xcp, ldx, ea, src, off, csre,
                            win_[layer], bin_[layer], AstripH, AstripL, KSW, kbase, KSs, zfill, N); break;
                case 3: aggr_strip_kernel<3><<<gA, 256, 0, stream>>>(xcp, ldx, ea, src, off, csre,
                            win_[layer], bin_[layer], AstripH, AstripL, KSW, kbase, KSs, zfill, N); break;
                default: aggr_strip_kernel<4><<<gA, 256, 0, stream>>>(xcp, ldx, ea, src, off, csre,
                            win_[layer], bin_[layer], AstripH, AstripL, KSW, kbase, KSs, zfill, N); break;
            }
            if (final3) {
                out3_strip_kernel<<<N, 256, 0, stream>>>(AstripH, AstripL, KSW, kbase, KSs,
                        wout_[layer], SC, bout_[layer], (float*)d_out, doInit, doLast);
            } else {
                int nk = (KSs + 31) / 32;
                gemm_mfma_kernel<<<gG, 256, 0, stream>>>(AstripH, AstripL, KSW,
                        Wh_[layer], Wl_[layer], SCp[layer], kbase, nk,
                        bout_[layer], outC, 516, N, doInit, doLast);
            }
            kbase += KSs;
        }
    };

    // p0: xc0[N,7] -> A      p1: A(+3) -> B       p2: B(+3) -> A
    // c0: A full    -> B     c1: B(+3) -> A       c2: A(+3) -> d_out
    run_layer(xc0,      7,   7,   0, bufA + 3, false);
    run_layer(bufA + 3, 516, 513, 1, bufB + 3, false);
    run_layer(bufB + 3, 516, 513, 2, bufA + 3, false);
    run_layer(bufA,     516, 516, 3, bufB + 3, false);
    run_layer(bufB + 3, 516, 513, 4, bufA + 3, false);
    run_layer(bufA + 3, 516, 513, 5, nullptr, true);
}